// Round 15
// baseline (121.292 us; speedup 1.0000x reference)
//
#include <hip/hip_runtime.h>
#include <hip/hip_bf16.h>

#define Bn 8
#define Cn 256
#define Hn 128
#define Wn 128
#define HWn (Hn * Wn)

typedef __attribute__((ext_vector_type(8))) short bfrag8;       // MFMA A/B frag (8 bf16)
typedef __attribute__((ext_vector_type(8))) unsigned short u16x8;
typedef __attribute__((ext_vector_type(4))) float f32x4;
typedef __attribute__((ext_vector_type(4))) unsigned int u32x4;

__device__ __forceinline__ float bf2f(unsigned short u) {
    unsigned int v = ((unsigned int)u) << 16;
    return __builtin_bit_cast(float, v);
}
__device__ __forceinline__ unsigned short f2bf(float f) {
    unsigned int u = __builtin_bit_cast(unsigned int, f);
    unsigned int lsb = (u >> 16) & 1u;
    u += 0x7fffu + lsb;   // round-to-nearest-even (finite inputs)
    return (unsigned short)(u >> 16);
}

// global->LDS DMA, 16 B per lane; dest = ldsbase + lane*16 (wave-uniform base)
__device__ __forceinline__ void load_lds16(const void* g, void* l) {
    __builtin_amdgcn_global_load_lds(
        (const __attribute__((address_space(1))) unsigned int*)g,
        (__attribute__((address_space(3))) unsigned int*)l,
        16, 0, 0);
}

// ---------------------------------------------------------------------------
// Kernel 0: w_comb2[o][c] = (sum_k w_W[o,k] * w_pc[k,c]) * w_dw[c], stored
// PRE-SWIZZLED in MFMA fragment order:
//   frag[ob][ks][lane][e] = w_comb2[ob*16 + (lane&15)][ks*32 + (lane>>4)*8 + e]
// ---------------------------------------------------------------------------
__global__ __launch_bounds__(256)
void build_wcomb(const float* __restrict__ w_dw,
                 const float* __restrict__ w_pc,
                 const float* __restrict__ w_W,
                 unsigned short* __restrict__ wfrag) {
    const int o = blockIdx.x;
    const int c = threadIdx.x;
    float acc = 0.f;
#pragma unroll 8
    for (int k = 0; k < Cn; ++k)
        acc = fmaf(w_W[o * Cn + k], w_pc[k * Cn + c], acc);
    const int ob = o >> 4, lr = o & 15;
    const int ks = c >> 5, lg = (c & 31) >> 3, e = c & 7;
    const int lane = (lg << 4) + lr;
    wfrag[((((ob << 3) + ks) << 6) + lane) * 8 + e] = f2bf(acc * w_dw[c]);
}

// ---------------------------------------------------------------------------
// Kernel 1: per 64-pixel tile, 512 threads. DMA x -> LDS f32 tile
// [256 ch][16 slots x 16B] with source-swizzled slots (slot q of row c holds
// pixel-chunk q ^ swz(c), swz(c)=(c^(c>>4))&15) so the transposed read is
// ~conflict-free. Convert phase: thread (pp,g) reads 32 f32 of pixel pp,
// fuses offset partial dot (w_off from padded LDS), packs bf16 -> x_t,
// shfl-reduces offsets -> tanh -> coords.
// ---------------------------------------------------------------------------
__global__ __launch_bounds__(512, 2)
void prep_kernel(const float* __restrict__ x,
                 const float* __restrict__ w_off,
                 const float* __restrict__ b_off,
                 unsigned short* __restrict__ x_t,    // [B*HW][C] bf16
                 float2* __restrict__ coords) {       // [B*HW] (ix, iy)
    __shared__ __align__(16) char tile[256 * 256];    // 256 ch x 64 px f32 (swizzled slots)
    __shared__ float wo[2][8][33];                    // padded w_off copy
    const int t = threadIdx.x;
    const int lane = t & 63;
    const int wv = t >> 6;                 // 0..7 (wave id)
    int blk = blockIdx.x;                  // 2048 blocks
    blk = ((blk & 7) << 8) | (blk >> 3);   // XCD swizzle: image b = XCD id
    const int b = blk >> 8;
    const int p0 = (blk & 255) << 6;
    const float* xp = x + ((size_t)b * Cn) * HWn + p0;

    // stage w_off into padded LDS (bank-spread reads in convert loop)
    {
        const int which = t >> 8, c = t & 255;
        wo[which][c >> 5][c & 31] = w_off[(which << 8) + c];
    }

    // ---- DMA phase: wave wv owns rows [wv*32, wv*32+32) as 8 quad-row DMAs
    {
        const int r = lane >> 4;           // row within quad
        const int q = lane & 15;           // LDS slot (16B units)
#pragma unroll
        for (int i = 0; i < 8; ++i) {
            const int cbase = (wv << 5) + (i << 2);     // wave-uniform
            const int c = cbase + r;
            const int swz = (c ^ (c >> 4)) & 15;
            const float* src = xp + (size_t)c * HWn + ((q ^ swz) << 2);
            load_lds16(src, tile + (cbase << 8));
        }
    }
    __syncthreads();   // drains DMA + orders wo

    // ---- convert phase: thread (pp = t>>3, g = t&7): 32 ch of pixel pp ----
    {
        const int pp = t >> 3;
        const int g = t & 7;
        float s0 = 0.f, s1 = 0.f;
        u16x8 res[4];
#pragma unroll
        for (int s = 0; s < 32; ++s) {
            const int c = (g << 5) + s;
            const int swz = (c ^ (c >> 4)) & 15;
            const int byte = (c << 8) + ((((pp >> 2) ^ swz)) << 4) + ((pp & 3) << 2);
            float v = *reinterpret_cast<const float*>(tile + byte);
            s0 = fmaf(v, wo[0][g][s], s0);
            s1 = fmaf(v, wo[1][g][s], s1);
            res[s >> 3][s & 7] = f2bf(v);
        }

        // reduce offset partials across the 8 threads of this pixel
        s0 += __shfl_xor(s0, 1); s0 += __shfl_xor(s0, 2); s0 += __shfl_xor(s0, 4);
        s1 += __shfl_xor(s1, 1); s1 += __shfl_xor(s1, 2); s1 += __shfl_xor(s1, 4);
        if (g == 0) {
            float o0 = tanhf(s0 + b_off[0]);
            float o1 = tanhf(s1 + b_off[1]);
            int p = p0 + pp;
            int yy = p >> 7, xx = p & 127;
            float gx = fminf(fmaxf(-1.f + xx * (2.f / 127.f) + o0, -1.f), 1.f);
            float gy = fminf(fmaxf(-1.f + yy * (2.f / 127.f) + o1, -1.f), 1.f);
            // ix = ((gx+1)*W - 1)/2 = 64*gx + 63.5 ; same for iy (H=W=128)
            coords[(size_t)b * HWn + p] = make_float2(gx * 64.f + 63.5f, gy * 64.f + 63.5f);
        }

        // write 32 ch (64 B) of pixel pp -> x_t, coalesced across g
        unsigned short* dst = x_t + ((size_t)(b * HWn + p0 + pp)) * Cn + (g << 5);
#pragma unroll
        for (int j = 0; j < 4; ++j)
            *reinterpret_cast<u32x4*>(dst + (j << 3)) = __builtin_bit_cast(u32x4, res[j]);
    }
}

// ---------------------------------------------------------------------------
// Kernel 2: per 32-pixel tile, 512 threads (8 waves). DMA-gather 4 corner LDS
// buffers (linear dest, source-swizzled chunks), sync, SINGLE blend pass
// (each (px,chunk) blended by exactly one thread, written in place into
// As[0] = samp), sync, MFMA (8 waves x 32-o slices) + fused epilogue.
//   out[o][p] = sum_c w_comb2[o][c]*samp[p][c] + b_W[o] + x[b][o][p]
// ---------------------------------------------------------------------------
__global__ __launch_bounds__(512, 2)
void main_kernel(const float* __restrict__ x,
                 const float* __restrict__ b_W,
                 const unsigned short* __restrict__ x_t,
                 const float2* __restrict__ coords,
                 const unsigned short* __restrict__ wfrag,
                 float* __restrict__ out) {
    __shared__ __align__(16) char As[4][32 * 512];   // 4 corners x 32px x 512B
    __shared__ __align__(16) float4 wts[32];         // per-pixel corner weights
    const int t = threadIdx.x;
    const int lane = t & 63;
    const int wid = t >> 6;          // 0..7
    int blk = blockIdx.x;            // 4096 blocks
    blk = ((blk & 7) << 9) | (blk >> 3);   // XCD swizzle: image b = XCD id
    const int b = blk >> 9;
    const int p0 = (blk & 511) << 5;       // 32-px tile
    const size_t pixbase = (size_t)b * HWn + p0;
    const unsigned short* xtb = x_t + (size_t)b * HWn * Cn;

    // ---- weights setup: one thread per pixel ----
    if (t < 32) {
        float2 co = coords[pixbase + t];
        float ix = co.x, iy = co.y;
        float fx = floorf(ix), fy = floorf(iy);
        int ix0 = (int)fx, iy0 = (int)fy;
        float wx1 = ix - fx, wy1 = iy - fy;
        float wx0 = 1.f - wx1, wy0 = 1.f - wy1;
        bool vx0 = (ix0 >= 0) && (ix0 < Wn);
        bool vx1 = (ix0 >= -1) && (ix0 < Wn - 1);
        bool vy0 = (iy0 >= 0) && (iy0 < Hn);
        bool vy1 = (iy0 >= -1) && (iy0 < Hn - 1);
        float4 w;
        w.x = (vy0 && vx0) ? wy0 * wx0 : 0.f;
        w.y = (vy0 && vx1) ? wy0 * wx1 : 0.f;
        w.z = (vy1 && vx0) ? wy1 * wx0 : 0.f;
        w.w = (vy1 && vx1) ? wy1 * wx1 : 0.f;
        wts[t] = w;
    }

    // ---- DMA gather: wave wid owns px [wid*4, wid*4+4) as 2 pixel-pairs ----
    {
        const int hp = lane >> 5;           // which pixel of the pair
        const int j = lane & 31;            // LDS chunk index (16B units)
        float2 co[2];
#pragma unroll
        for (int i = 0; i < 2; ++i)
            co[i] = coords[pixbase + (wid << 2) + (i << 1) + hp];

#pragma unroll
        for (int i = 0; i < 2; ++i) {
            const int p = (wid << 2) + (i << 1);   // pair base (wave-uniform)
            const int px = p + hp;                 // this lane's pixel
            float ix = co[i].x, iy = co[i].y;
            int ix0 = (int)floorf(ix), iy0 = (int)floorf(iy);
            int cx0 = min(max(ix0, 0), Wn - 1), cx1 = min(max(ix0 + 1, 0), Wn - 1);
            int cy0 = min(max(iy0, 0), Hn - 1), cy1 = min(max(iy0 + 1, 0), Hn - 1);
            const int gch = (j ^ (px & 15)) << 3;  // swizzled global channel base
            const unsigned short* s00 = xtb + (size_t)(cy0 * Wn + cx0) * Cn + gch;
            const unsigned short* s01 = xtb + (size_t)(cy0 * Wn + cx1) * Cn + gch;
            const unsigned short* s10 = xtb + (size_t)(cy1 * Wn + cx0) * Cn + gch;
            const unsigned short* s11 = xtb + (size_t)(cy1 * Wn + cx1) * Cn + gch;
            load_lds16(s00, &As[0][p << 9]);
            load_lds16(s01, &As[1][p << 9]);
            load_lds16(s10, &As[2][p << 9]);
            load_lds16(s11, &As[3][p << 9]);
        }
    }
    __syncthreads();   // drains DMA (vmcnt) + orders wts

    // ---- blend pass: each (px, chunk) by exactly one thread, in place ----
    {
        const int px = t >> 4;             // 0..31
        const float4 w = wts[px];
#pragma unroll
        for (int q = 0; q < 2; ++q) {
            const int kc = (t & 15) + (q << 4);          // 0..31
            const int off = (px << 9) + ((kc ^ (px & 15)) << 4);
            u16x8 c00 = *reinterpret_cast<const u16x8*>(&As[0][off]);
            u16x8 c01 = *reinterpret_cast<const u16x8*>(&As[1][off]);
            u16x8 c10 = *reinterpret_cast<const u16x8*>(&As[2][off]);
            u16x8 c11 = *reinterpret_cast<const u16x8*>(&As[3][off]);
            u16x8 res;
#pragma unroll
            for (int e = 0; e < 8; ++e) {
                float r = w.x * bf2f(c00[e]) + w.y * bf2f(c01[e])
                        + w.z * bf2f(c10[e]) + w.w * bf2f(c11[e]);
                res[e] = f2bf(r);
            }
            *reinterpret_cast<u16x8*>(&As[0][off]) = res;  // samp in place
        }
    }
    __syncthreads();

    // ---- MFMA phase: 8 waves; wave wid owns o-range [wid*32, +32), all 32 px
    const int lr = lane & 15;
    const int lg = lane >> 4;
    f32x4 acc[2][2];
#pragma unroll
    for (int m = 0; m < 2; ++m)
#pragma unroll
        for (int n = 0; n < 2; ++n)
            acc[m][n] = (f32x4){0.f, 0.f, 0.f, 0.f};

#pragma unroll
    for (int ks = 0; ks < 8; ++ks) {
        bfrag8 a[2], bb[2];
        const int kc = (ks << 2) + lg;           // 16B chunk index 0..31
#pragma unroll
        for (int n = 0; n < 2; ++n) {
            const int pr = (n << 4) + lr;
            const int off = (pr << 9) + ((kc ^ (pr & 15)) << 4);
            bb[n] = *reinterpret_cast<const bfrag8*>(&As[0][off]);
        }
#pragma unroll
        for (int m = 0; m < 2; ++m) {
            // coalesced fragment load: 64 lanes x 16 B contiguous (1 KB)
            const int ob = (wid << 1) + m;
            const unsigned short* src = wfrag + ((((ob << 3) + ks) << 6) + lane) * 8;
            a[m] = *reinterpret_cast<const bfrag8*>(src);
        }
#pragma unroll
        for (int m = 0; m < 2; ++m)
#pragma unroll
            for (int n = 0; n < 2; ++n)
                acc[m][n] = __builtin_amdgcn_mfma_f32_16x16x32_bf16(a[m], bb[n], acc[m][n], 0, 0, 0);
    }

    // ---- epilogue: D col = lane&15 (pixel), row = lg*4+reg (o); nt out-store
#pragma unroll
    for (int m = 0; m < 2; ++m) {
#pragma unroll
        for (int r = 0; r < 4; ++r) {
            int o = (wid << 5) + (m << 4) + (lg << 2) + r;
            float bw = b_W[o];
            size_t rowbase = ((size_t)b * Cn + o) * HWn + p0;
#pragma unroll
            for (int n = 0; n < 2; ++n) {
                size_t idx = rowbase + (n << 4) + lr;
                __builtin_nontemporal_store(acc[m][n][r] + bw + x[idx], &out[idx]);
            }
        }
    }
}

extern "C" void kernel_launch(void* const* d_in, const int* in_sizes, int n_in,
                              void* d_out, int out_size, void* d_ws, size_t ws_size,
                              hipStream_t stream) {
    const float* x     = (const float*)d_in[0];
    const float* w_dw  = (const float*)d_in[1];
    const float* w_off = (const float*)d_in[2];
    const float* b_off = (const float*)d_in[3];
    const float* w_pc  = (const float*)d_in[4];
    const float* w_W   = (const float*)d_in[5];
    const float* b_W   = (const float*)d_in[6];
    float* out = (float*)d_out;

    char* ws = (char*)d_ws;
    unsigned short* x_t   = (unsigned short*)ws;                        // 67,108,864 B
    float2* coords        = (float2*)(ws + 67108864);                   //  1,048,576 B
    unsigned short* wcomb = (unsigned short*)(ws + 67108864 + 1048576); //    131,072 B

    build_wcomb<<<dim3(256), dim3(256), 0, stream>>>(w_dw, w_pc, w_W, wcomb);
    prep_kernel<<<dim3(2048), dim3(512), 0, stream>>>(x, w_off, b_off, x_t, coords);
    main_kernel<<<dim3(4096), dim3(512), 0, stream>>>(x, b_W, x_t, coords, wcomb, out);
}

// Round 16
// 118.231 us; speedup vs baseline: 1.0259x; 1.0259x over previous
//
#include <hip/hip_runtime.h>
#include <hip/hip_bf16.h>

#define Bn 8
#define Cn 256
#define Hn 128
#define Wn 128
#define HWn (Hn * Wn)

typedef __attribute__((ext_vector_type(8))) short bfrag8;       // MFMA A/B frag (8 bf16)
typedef __attribute__((ext_vector_type(8))) unsigned short u16x8;
typedef __attribute__((ext_vector_type(4))) float f32x4;
typedef __attribute__((ext_vector_type(4))) unsigned int u32x4;

__device__ __forceinline__ float bf2f(unsigned short u) {
    unsigned int v = ((unsigned int)u) << 16;
    return __builtin_bit_cast(float, v);
}
__device__ __forceinline__ unsigned short f2bf(float f) {
    unsigned int u = __builtin_bit_cast(unsigned int, f);
    unsigned int lsb = (u >> 16) & 1u;
    u += 0x7fffu + lsb;   // round-to-nearest-even (finite inputs)
    return (unsigned short)(u >> 16);
}

// global->LDS DMA, 16 B per lane; dest = ldsbase + lane*16 (wave-uniform base)
__device__ __forceinline__ void load_lds16(const void* g, void* l) {
    __builtin_amdgcn_global_load_lds(
        (const __attribute__((address_space(1))) unsigned int*)g,
        (__attribute__((address_space(3))) unsigned int*)l,
        16, 0, 0);
}

// ---------------------------------------------------------------------------
// Kernel 0: w_comb2[o][c] = (sum_k w_W[o,k] * w_pc[k,c]) * w_dw[c], stored
// PRE-SWIZZLED in MFMA fragment order:
//   frag[ob][ks][lane][e] = w_comb2[ob*16 + (lane&15)][ks*32 + (lane>>4)*8 + e]
// ---------------------------------------------------------------------------
__global__ __launch_bounds__(256)
void build_wcomb(const float* __restrict__ w_dw,
                 const float* __restrict__ w_pc,
                 const float* __restrict__ w_W,
                 unsigned short* __restrict__ wfrag) {
    const int o = blockIdx.x;
    const int c = threadIdx.x;
    float acc = 0.f;
#pragma unroll 8
    for (int k = 0; k < Cn; ++k)
        acc = fmaf(w_W[o * Cn + k], w_pc[k * Cn + c], acc);
    const int ob = o >> 4, lr = o & 15;
    const int ks = c >> 5, lg = (c & 31) >> 3, e = c & 7;
    const int lane = (lg << 4) + lr;
    wfrag[((((ob << 3) + ks) << 6) + lane) * 8 + e] = f2bf(acc * w_dw[c]);
}

// ---------------------------------------------------------------------------
// Kernel 1: per 512-pixel tile, 512 threads, 1 block/CU (grid=256). Channels
// in 8 slices of 32; slice rows are 2 KB CONTIGUOUS global reads via
// global_load_lds (DRAM-page-efficient), double-buffered: dma(sl+1) overlaps
// convert(sl). Convert: thread = 1 pixel, reads its 32-f32 column (2-way bank
// = free), fuses w_off partial dot, packs bf16 -> x_t. After 8 slices each
// thread holds the FULL 256-ch offset dot for its pixel -> tanh -> coords.
// ---------------------------------------------------------------------------
__global__ __launch_bounds__(512, 1)
void prep_kernel(const float* __restrict__ x,
                 const float* __restrict__ w_off,
                 const float* __restrict__ b_off,
                 unsigned short* __restrict__ x_t,    // [B*HW][C] bf16
                 float2* __restrict__ coords) {       // [B*HW] (ix, iy)
    __shared__ __align__(16) char bufs[2][32 * 512 * 4];  // 2 x 64 KB slice bufs
    __shared__ float wo[2][256];
    const int t = threadIdx.x;
    const int lane = t & 63;
    const int wv = t >> 6;                 // 0..7 (wave id)
    int blk = blockIdx.x;                  // 256 blocks
    blk = ((blk & 7) << 5) | (blk >> 3);   // XCD swizzle: image b = XCD id
    const int b = blk >> 5;
    const int p0 = (blk & 31) << 9;        // 512-px tile
    const float* xp = x + ((size_t)b * Cn) * HWn + p0;

    // stage w_off (broadcast reads in convert)
    wo[t >> 8][t & 255] = w_off[t];

    float s0 = 0.f, s1 = 0.f;

    // DMA one 32-ch slice into buf: rows are 2 KB contiguous (2 x 1 KB DMA)
    auto dma = [&](int sl, char* buf) {
#pragma unroll
        for (int i = 0; i < 4; ++i) {
            const int cl = (wv << 2) + i;                       // wave-uniform
            const float* src = xp + (size_t)((sl << 5) + cl) * HWn + (lane << 2);
            load_lds16(src,       buf + (cl << 11));
            load_lds16(src + 256, buf + (cl << 11) + 1024);
        }
    };

    // convert one slice: this thread's pixel column (32 f32), fused dot+pack
    auto conv = [&](int sl, const char* buf) {
        const float* bf = (const float*)buf;
        u16x8 res[4];
#pragma unroll
        for (int s = 0; s < 32; ++s) {
            float v = bf[(s << 9) + t];
            s0 = fmaf(v, wo[0][(sl << 5) + s], s0);
            s1 = fmaf(v, wo[1][(sl << 5) + s], s1);
            res[s >> 3][s & 7] = f2bf(v);
        }
        unsigned short* dst = x_t + ((size_t)(b * HWn + p0 + t)) * Cn + (sl << 5);
#pragma unroll
        for (int j = 0; j < 4; ++j)
            *reinterpret_cast<u32x4*>(dst + (j << 3)) = __builtin_bit_cast(u32x4, res[j]);
    };

    dma(0, bufs[0]);
    __syncthreads();                       // slice 0 landed (+ wo visible)
#pragma unroll
    for (int sl = 1; sl < 8; ++sl) {
        dma(sl, bufs[sl & 1]);             // stream next slice ...
        conv(sl - 1, bufs[(sl - 1) & 1]);  // ... under this convert
        __syncthreads();
    }
    conv(7, bufs[1]);

    // full 256-ch offset dot now in s0,s1 for this thread's pixel
    float o0 = tanhf(s0 + b_off[0]);
    float o1 = tanhf(s1 + b_off[1]);
    int p = p0 + t;
    int yy = p >> 7, xx = p & 127;
    float gx = fminf(fmaxf(-1.f + xx * (2.f / 127.f) + o0, -1.f), 1.f);
    float gy = fminf(fmaxf(-1.f + yy * (2.f / 127.f) + o1, -1.f), 1.f);
    // ix = ((gx+1)*W - 1)/2 = 64*gx + 63.5 ; same for iy (H=W=128)
    coords[(size_t)b * HWn + p] = make_float2(gx * 64.f + 63.5f, gy * 64.f + 63.5f);
}

// ---------------------------------------------------------------------------
// Kernel 2: per 32-pixel tile, 512 threads (8 waves). DMA-gather 4 corner LDS
// buffers (linear dest, source-swizzled chunks), sync, SINGLE blend pass
// (each (px,chunk) blended by exactly one thread, written in place into
// As[0] = samp), sync, MFMA (8 waves x 32-o slices) + fused epilogue.
//   out[o][p] = sum_c w_comb2[o][c]*samp[p][c] + b_W[o] + x[b][o][p]
// ---------------------------------------------------------------------------
__global__ __launch_bounds__(512, 2)
void main_kernel(const float* __restrict__ x,
                 const float* __restrict__ b_W,
                 const unsigned short* __restrict__ x_t,
                 const float2* __restrict__ coords,
                 const unsigned short* __restrict__ wfrag,
                 float* __restrict__ out) {
    __shared__ __align__(16) char As[4][32 * 512];   // 4 corners x 32px x 512B
    __shared__ __align__(16) float4 wts[32];         // per-pixel corner weights
    const int t = threadIdx.x;
    const int lane = t & 63;
    const int wid = t >> 6;          // 0..7
    int blk = blockIdx.x;            // 4096 blocks
    blk = ((blk & 7) << 9) | (blk >> 3);   // XCD swizzle: image b = XCD id
    const int b = blk >> 9;
    const int p0 = (blk & 511) << 5;       // 32-px tile
    const size_t pixbase = (size_t)b * HWn + p0;
    const unsigned short* xtb = x_t + (size_t)b * HWn * Cn;

    // ---- weights setup: one thread per pixel ----
    if (t < 32) {
        float2 co = coords[pixbase + t];
        float ix = co.x, iy = co.y;
        float fx = floorf(ix), fy = floorf(iy);
        int ix0 = (int)fx, iy0 = (int)fy;
        float wx1 = ix - fx, wy1 = iy - fy;
        float wx0 = 1.f - wx1, wy0 = 1.f - wy1;
        bool vx0 = (ix0 >= 0) && (ix0 < Wn);
        bool vx1 = (ix0 >= -1) && (ix0 < Wn - 1);
        bool vy0 = (iy0 >= 0) && (iy0 < Hn);
        bool vy1 = (iy0 >= -1) && (iy0 < Hn - 1);
        float4 w;
        w.x = (vy0 && vx0) ? wy0 * wx0 : 0.f;
        w.y = (vy0 && vx1) ? wy0 * wx1 : 0.f;
        w.z = (vy1 && vx0) ? wy1 * wx0 : 0.f;
        w.w = (vy1 && vx1) ? wy1 * wx1 : 0.f;
        wts[t] = w;
    }

    // ---- DMA gather: wave wid owns px [wid*4, wid*4+4) as 2 pixel-pairs ----
    {
        const int hp = lane >> 5;           // which pixel of the pair
        const int j = lane & 31;            // LDS chunk index (16B units)
        float2 co[2];
#pragma unroll
        for (int i = 0; i < 2; ++i)
            co[i] = coords[pixbase + (wid << 2) + (i << 1) + hp];

#pragma unroll
        for (int i = 0; i < 2; ++i) {
            const int p = (wid << 2) + (i << 1);   // pair base (wave-uniform)
            const int px = p + hp;                 // this lane's pixel
            float ix = co[i].x, iy = co[i].y;
            int ix0 = (int)floorf(ix), iy0 = (int)floorf(iy);
            int cx0 = min(max(ix0, 0), Wn - 1), cx1 = min(max(ix0 + 1, 0), Wn - 1);
            int cy0 = min(max(iy0, 0), Hn - 1), cy1 = min(max(iy0 + 1, 0), Hn - 1);
            const int gch = (j ^ (px & 15)) << 3;  // swizzled global channel base
            const unsigned short* s00 = xtb + (size_t)(cy0 * Wn + cx0) * Cn + gch;
            const unsigned short* s01 = xtb + (size_t)(cy0 * Wn + cx1) * Cn + gch;
            const unsigned short* s10 = xtb + (size_t)(cy1 * Wn + cx0) * Cn + gch;
            const unsigned short* s11 = xtb + (size_t)(cy1 * Wn + cx1) * Cn + gch;
            load_lds16(s00, &As[0][p << 9]);
            load_lds16(s01, &As[1][p << 9]);
            load_lds16(s10, &As[2][p << 9]);
            load_lds16(s11, &As[3][p << 9]);
        }
    }
    __syncthreads();   // drains DMA (vmcnt) + orders wts

    // ---- blend pass: each (px, chunk) by exactly one thread, in place ----
    {
        const int px = t >> 4;             // 0..31
        const float4 w = wts[px];
#pragma unroll
        for (int q = 0; q < 2; ++q) {
            const int kc = (t & 15) + (q << 4);          // 0..31
            const int off = (px << 9) + ((kc ^ (px & 15)) << 4);
            u16x8 c00 = *reinterpret_cast<const u16x8*>(&As[0][off]);
            u16x8 c01 = *reinterpret_cast<const u16x8*>(&As[1][off]);
            u16x8 c10 = *reinterpret_cast<const u16x8*>(&As[2][off]);
            u16x8 c11 = *reinterpret_cast<const u16x8*>(&As[3][off]);
            u16x8 res;
#pragma unroll
            for (int e = 0; e < 8; ++e) {
                float r = w.x * bf2f(c00[e]) + w.y * bf2f(c01[e])
                        + w.z * bf2f(c10[e]) + w.w * bf2f(c11[e]);
                res[e] = f2bf(r);
            }
            *reinterpret_cast<u16x8*>(&As[0][off]) = res;  // samp in place
        }
    }
    __syncthreads();

    // ---- MFMA phase: 8 waves; wave wid owns o-range [wid*32, +32), all 32 px
    const int lr = lane & 15;
    const int lg = lane >> 4;
    f32x4 acc[2][2];
#pragma unroll
    for (int m = 0; m < 2; ++m)
#pragma unroll
        for (int n = 0; n < 2; ++n)
            acc[m][n] = (f32x4){0.f, 0.f, 0.f, 0.f};

#pragma unroll
    for (int ks = 0; ks < 8; ++ks) {
        bfrag8 a[2], bb[2];
        const int kc = (ks << 2) + lg;           // 16B chunk index 0..31
#pragma unroll
        for (int n = 0; n < 2; ++n) {
            const int pr = (n << 4) + lr;
            const int off = (pr << 9) + ((kc ^ (pr & 15)) << 4);
            bb[n] = *reinterpret_cast<const bfrag8*>(&As[0][off]);
        }
#pragma unroll
        for (int m = 0; m < 2; ++m) {
            // coalesced fragment load: 64 lanes x 16 B contiguous (1 KB)
            const int ob = (wid << 1) + m;
            const unsigned short* src = wfrag + ((((ob << 3) + ks) << 6) + lane) * 8;
            a[m] = *reinterpret_cast<const bfrag8*>(src);
        }
#pragma unroll
        for (int m = 0; m < 2; ++m)
#pragma unroll
            for (int n = 0; n < 2; ++n)
                acc[m][n] = __builtin_amdgcn_mfma_f32_16x16x32_bf16(a[m], bb[n], acc[m][n], 0, 0, 0);
    }

    // ---- epilogue: D col = lane&15 (pixel), row = lg*4+reg (o); nt out-store
#pragma unroll
    for (int m = 0; m < 2; ++m) {
#pragma unroll
        for (int r = 0; r < 4; ++r) {
            int o = (wid << 5) + (m << 4) + (lg << 2) + r;
            float bw = b_W[o];
            size_t rowbase = ((size_t)b * Cn + o) * HWn + p0;
#pragma unroll
            for (int n = 0; n < 2; ++n) {
                size_t idx = rowbase + (n << 4) + lr;
                __builtin_nontemporal_store(acc[m][n][r] + bw + x[idx], &out[idx]);
            }
        }
    }
}

extern "C" void kernel_launch(void* const* d_in, const int* in_sizes, int n_in,
                              void* d_out, int out_size, void* d_ws, size_t ws_size,
                              hipStream_t stream) {
    const float* x     = (const float*)d_in[0];
    const float* w_dw  = (const float*)d_in[1];
    const float* w_off = (const float*)d_in[2];
    const float* b_off = (const float*)d_in[3];
    const float* w_pc  = (const float*)d_in[4];
    const float* w_W   = (const float*)d_in[5];
    const float* b_W   = (const float*)d_in[6];
    float* out = (float*)d_out;

    char* ws = (char*)d_ws;
    unsigned short* x_t   = (unsigned short*)ws;                        // 67,108,864 B
    float2* coords        = (float2*)(ws + 67108864);                   //  1,048,576 B
    unsigned short* wcomb = (unsigned short*)(ws + 67108864 + 1048576); //    131,072 B

    build_wcomb<<<dim3(256), dim3(256), 0, stream>>>(w_dw, w_pc, w_W, wcomb);
    prep_kernel<<<dim3(256), dim3(512), 0, stream>>>(x, w_off, b_off, x_t, coords);
    main_kernel<<<dim3(4096), dim3(512), 0, stream>>>(x, b_W, x_t, coords, wcomb, out);
}

// Round 17
// 116.166 us; speedup vs baseline: 1.0441x; 1.0178x over previous
//
#include <hip/hip_runtime.h>
#include <hip/hip_bf16.h>

#define Bn 8
#define Cn 256
#define Hn 128
#define Wn 128
#define HWn (Hn * Wn)

typedef __attribute__((ext_vector_type(8))) short bfrag8;       // MFMA A/B frag (8 bf16)
typedef __attribute__((ext_vector_type(8))) unsigned short u16x8;
typedef __attribute__((ext_vector_type(4))) float f32x4;
typedef __attribute__((ext_vector_type(4))) unsigned int u32x4;

__device__ __forceinline__ float bf2f(unsigned short u) {
    unsigned int v = ((unsigned int)u) << 16;
    return __builtin_bit_cast(float, v);
}
__device__ __forceinline__ unsigned short f2bf(float f) {
    unsigned int u = __builtin_bit_cast(unsigned int, f);
    unsigned int lsb = (u >> 16) & 1u;
    u += 0x7fffu + lsb;   // round-to-nearest-even (finite inputs)
    return (unsigned short)(u >> 16);
}

// global->LDS DMA, 16 B per lane; dest = ldsbase + lane*16 (wave-uniform base)
__device__ __forceinline__ void load_lds16(const void* g, void* l) {
    __builtin_amdgcn_global_load_lds(
        (const __attribute__((address_space(1))) unsigned int*)g,
        (__attribute__((address_space(3))) unsigned int*)l,
        16, 0, 0);
}

// ---------------------------------------------------------------------------
// Kernel 0: w_comb2[o][c] = (sum_k w_W[o,k] * w_pc[k,c]) * w_dw[c], stored
// PRE-SWIZZLED in MFMA fragment order:
//   frag[ob][ks][lane][e] = w_comb2[ob*16 + (lane&15)][ks*32 + (lane>>4)*8 + e]
// ---------------------------------------------------------------------------
__global__ __launch_bounds__(256)
void build_wcomb(const float* __restrict__ w_dw,
                 const float* __restrict__ w_pc,
                 const float* __restrict__ w_W,
                 unsigned short* __restrict__ wfrag) {
    const int o = blockIdx.x;
    const int c = threadIdx.x;
    float acc = 0.f;
#pragma unroll 8
    for (int k = 0; k < Cn; ++k)
        acc = fmaf(w_W[o * Cn + k], w_pc[k * Cn + c], acc);
    const int ob = o >> 4, lr = o & 15;
    const int ks = c >> 5, lg = (c & 31) >> 3, e = c & 7;
    const int lane = (lg << 4) + lr;
    wfrag[((((ob << 3) + ks) << 6) + lane) * 8 + e] = f2bf(acc * w_dw[c]);
}

// ---------------------------------------------------------------------------
// Kernel 1: per 64-pixel tile, 512 threads, 2 blocks/CU. DMA x -> LDS f32
// tile [256 ch][16 slots x 16B], slots source-swizzled (slot q of row c holds
// pixel-chunk q ^ swz(c), swz(c)=(c^(c>>4))&15). Convert: PAIR-COALESCED —
// wave handles 2 px/iteration, lane owns 8 consecutive channels of one px,
// so each wave x_t store is a CONTIGUOUS 1 KB (16 full 64B lines, no partial
// line writes). Offset dot reduced per 32-lane half via shfl_xor; w_off
// staged transposed for conflict-free LDS reads.
// ---------------------------------------------------------------------------
__global__ __launch_bounds__(512, 2)
void prep_kernel(const float* __restrict__ x,
                 const float* __restrict__ w_off,
                 const float* __restrict__ b_off,
                 unsigned short* __restrict__ x_t,    // [B*HW][C] bf16
                 float2* __restrict__ coords) {       // [B*HW] (ix, iy)
    __shared__ __align__(16) char tile[256 * 256];    // 256 ch x 64 px f32 (swizzled slots)
    __shared__ float woT[2][256];                     // woT[s][j*32+octet] = w_off[s*256+octet*8+j]
    const int t = threadIdx.x;
    const int lane = t & 63;
    const int wv = t >> 6;                 // 0..7 (wave id)
    int blk = blockIdx.x;                  // 2048 blocks
    blk = ((blk & 7) << 8) | (blk >> 3);   // XCD swizzle: image b = XCD id
    const int b = blk >> 8;
    const int p0 = (blk & 255) << 6;
    const float* xp = x + ((size_t)b * Cn) * HWn + p0;

    // stage w_off transposed (conflict-free reads in convert)
    {
        const int s = t >> 8, c = t & 255;
        woT[s][((c & 7) << 5) | (c >> 3)] = w_off[(s << 8) + c];
    }

    // ---- DMA phase: wave wv owns rows [wv*32, wv*32+32) as 8 quad-row DMAs
    {
        const int r = lane >> 4;           // row within quad
        const int q = lane & 15;           // LDS slot (16B units)
#pragma unroll
        for (int i = 0; i < 8; ++i) {
            const int cbase = (wv << 5) + (i << 2);     // wave-uniform
            const int c = cbase + r;
            const int swz = (c ^ (c >> 4)) & 15;
            const float* src = xp + (size_t)c * HWn + ((q ^ swz) << 2);
            load_lds16(src, tile + (cbase << 8));
        }
    }
    __syncthreads();   // drains DMA + orders woT

    // ---- convert: wave wv owns px [wv*8, +8) as 4 pairs; lane: m=l>>5 (pair
    // member), octet=l&31 (8-channel group). Wave store = contiguous 1 KB.
    {
        const int m = lane >> 5;
        const int octet = lane & 31;
#pragma unroll
        for (int i = 0; i < 4; ++i) {
            const int px = (wv << 3) + (i << 1) + m;   // tile-local 0..63
            float s0 = 0.f, s1 = 0.f;
            u16x8 res;
#pragma unroll
            for (int j = 0; j < 8; ++j) {
                const int c = (octet << 3) + j;
                const int swz = (c ^ (c >> 4)) & 15;
                const int byte = (c << 8) + ((((px >> 2) ^ swz)) << 4) + ((px & 3) << 2);
                float v = *reinterpret_cast<const float*>(tile + byte);
                s0 = fmaf(v, woT[0][(j << 5) + octet], s0);
                s1 = fmaf(v, woT[1][(j << 5) + octet], s1);
                res[j] = f2bf(v);
            }
            // coalesced wave store: lanes cover x_t[px(pair)][0..256) = 1 KB
            *reinterpret_cast<u16x8*>(
                x_t + ((size_t)(b * HWn + p0 + px)) * Cn + (octet << 3)) = res;

            // offset reduce within each 32-lane half (one pixel per half)
            s0 += __shfl_xor(s0, 1); s0 += __shfl_xor(s0, 2); s0 += __shfl_xor(s0, 4);
            s0 += __shfl_xor(s0, 8); s0 += __shfl_xor(s0, 16);
            s1 += __shfl_xor(s1, 1); s1 += __shfl_xor(s1, 2); s1 += __shfl_xor(s1, 4);
            s1 += __shfl_xor(s1, 8); s1 += __shfl_xor(s1, 16);
            if (octet == 0) {
                float o0 = tanhf(s0 + b_off[0]);
                float o1 = tanhf(s1 + b_off[1]);
                int p = p0 + px;
                int yy = p >> 7, xx = p & 127;
                float gx = fminf(fmaxf(-1.f + xx * (2.f / 127.f) + o0, -1.f), 1.f);
                float gy = fminf(fmaxf(-1.f + yy * (2.f / 127.f) + o1, -1.f), 1.f);
                // ix = ((gx+1)*W - 1)/2 = 64*gx + 63.5 ; same for iy (H=W=128)
                coords[(size_t)b * HWn + p] = make_float2(gx * 64.f + 63.5f, gy * 64.f + 63.5f);
            }
        }
    }
}

// ---------------------------------------------------------------------------
// Kernel 2: per 32-pixel tile, 512 threads (8 waves). DMA-gather 4 corner LDS
// buffers (linear dest, source-swizzled chunks), sync, SINGLE blend pass
// (each (px,chunk) blended by exactly one thread, written in place into
// As[0] = samp), sync, MFMA (8 waves x 32-o slices) + fused epilogue.
//   out[o][p] = sum_c w_comb2[o][c]*samp[p][c] + b_W[o] + x[b][o][p]
// ---------------------------------------------------------------------------
__global__ __launch_bounds__(512, 2)
void main_kernel(const float* __restrict__ x,
                 const float* __restrict__ b_W,
                 const unsigned short* __restrict__ x_t,
                 const float2* __restrict__ coords,
                 const unsigned short* __restrict__ wfrag,
                 float* __restrict__ out) {
    __shared__ __align__(16) char As[4][32 * 512];   // 4 corners x 32px x 512B
    __shared__ __align__(16) float4 wts[32];         // per-pixel corner weights
    const int t = threadIdx.x;
    const int lane = t & 63;
    const int wid = t >> 6;          // 0..7
    int blk = blockIdx.x;            // 4096 blocks
    blk = ((blk & 7) << 9) | (blk >> 3);   // XCD swizzle: image b = XCD id
    const int b = blk >> 9;
    const int p0 = (blk & 511) << 5;       // 32-px tile
    const size_t pixbase = (size_t)b * HWn + p0;
    const unsigned short* xtb = x_t + (size_t)b * HWn * Cn;

    // ---- weights setup: one thread per pixel ----
    if (t < 32) {
        float2 co = coords[pixbase + t];
        float ix = co.x, iy = co.y;
        float fx = floorf(ix), fy = floorf(iy);
        int ix0 = (int)fx, iy0 = (int)fy;
        float wx1 = ix - fx, wy1 = iy - fy;
        float wx0 = 1.f - wx1, wy0 = 1.f - wy1;
        bool vx0 = (ix0 >= 0) && (ix0 < Wn);
        bool vx1 = (ix0 >= -1) && (ix0 < Wn - 1);
        bool vy0 = (iy0 >= 0) && (iy0 < Hn);
        bool vy1 = (iy0 >= -1) && (iy0 < Hn - 1);
        float4 w;
        w.x = (vy0 && vx0) ? wy0 * wx0 : 0.f;
        w.y = (vy0 && vx1) ? wy0 * wx1 : 0.f;
        w.z = (vy1 && vx0) ? wy1 * wx0 : 0.f;
        w.w = (vy1 && vx1) ? wy1 * wx1 : 0.f;
        wts[t] = w;
    }

    // ---- DMA gather: wave wid owns px [wid*4, wid*4+4) as 2 pixel-pairs ----
    {
        const int hp = lane >> 5;           // which pixel of the pair
        const int j = lane & 31;            // LDS chunk index (16B units)
        float2 co[2];
#pragma unroll
        for (int i = 0; i < 2; ++i)
            co[i] = coords[pixbase + (wid << 2) + (i << 1) + hp];

#pragma unroll
        for (int i = 0; i < 2; ++i) {
            const int p = (wid << 2) + (i << 1);   // pair base (wave-uniform)
            const int px = p + hp;                 // this lane's pixel
            float ix = co[i].x, iy = co[i].y;
            int ix0 = (int)floorf(ix), iy0 = (int)floorf(iy);
            int cx0 = min(max(ix0, 0), Wn - 1), cx1 = min(max(ix0 + 1, 0), Wn - 1);
            int cy0 = min(max(iy0, 0), Hn - 1), cy1 = min(max(iy0 + 1, 0), Hn - 1);
            const int gch = (j ^ (px & 15)) << 3;  // swizzled global channel base
            const unsigned short* s00 = xtb + (size_t)(cy0 * Wn + cx0) * Cn + gch;
            const unsigned short* s01 = xtb + (size_t)(cy0 * Wn + cx1) * Cn + gch;
            const unsigned short* s10 = xtb + (size_t)(cy1 * Wn + cx0) * Cn + gch;
            const unsigned short* s11 = xtb + (size_t)(cy1 * Wn + cx1) * Cn + gch;
            load_lds16(s00, &As[0][p << 9]);
            load_lds16(s01, &As[1][p << 9]);
            load_lds16(s10, &As[2][p << 9]);
            load_lds16(s11, &As[3][p << 9]);
        }
    }
    __syncthreads();   // drains DMA (vmcnt) + orders wts

    // ---- blend pass: each (px, chunk) by exactly one thread, in place ----
    {
        const int px = t >> 4;             // 0..31
        const float4 w = wts[px];
#pragma unroll
        for (int q = 0; q < 2; ++q) {
            const int kc = (t & 15) + (q << 4);          // 0..31
            const int off = (px << 9) + ((kc ^ (px & 15)) << 4);
            u16x8 c00 = *reinterpret_cast<const u16x8*>(&As[0][off]);
            u16x8 c01 = *reinterpret_cast<const u16x8*>(&As[1][off]);
            u16x8 c10 = *reinterpret_cast<const u16x8*>(&As[2][off]);
            u16x8 c11 = *reinterpret_cast<const u16x8*>(&As[3][off]);
            u16x8 res;
#pragma unroll
            for (int e = 0; e < 8; ++e) {
                float r = w.x * bf2f(c00[e]) + w.y * bf2f(c01[e])
                        + w.z * bf2f(c10[e]) + w.w * bf2f(c11[e]);
                res[e] = f2bf(r);
            }
            *reinterpret_cast<u16x8*>(&As[0][off]) = res;  // samp in place
        }
    }
    __syncthreads();

    // ---- MFMA phase: 8 waves; wave wid owns o-range [wid*32, +32), all 32 px
    const int lr = lane & 15;
    const int lg = lane >> 4;
    f32x4 acc[2][2];
#pragma unroll
    for (int m = 0; m < 2; ++m)
#pragma unroll
        for (int n = 0; n < 2; ++n)
            acc[m][n] = (f32x4){0.f, 0.f, 0.f, 0.f};

#pragma unroll
    for (int ks = 0; ks < 8; ++ks) {
        bfrag8 a[2], bb[2];
        const int kc = (ks << 2) + lg;           // 16B chunk index 0..31
#pragma unroll
        for (int n = 0; n < 2; ++n) {
            const int pr = (n << 4) + lr;
            const int off = (pr << 9) + ((kc ^ (pr & 15)) << 4);
            bb[n] = *reinterpret_cast<const bfrag8*>(&As[0][off]);
        }
#pragma unroll
        for (int m = 0; m < 2; ++m) {
            // coalesced fragment load: 64 lanes x 16 B contiguous (1 KB)
            const int ob = (wid << 1) + m;
            const unsigned short* src = wfrag + ((((ob << 3) + ks) << 6) + lane) * 8;
            a[m] = *reinterpret_cast<const bfrag8*>(src);
        }
#pragma unroll
        for (int m = 0; m < 2; ++m)
#pragma unroll
            for (int n = 0; n < 2; ++n)
                acc[m][n] = __builtin_amdgcn_mfma_f32_16x16x32_bf16(a[m], bb[n], acc[m][n], 0, 0, 0);
    }

    // ---- epilogue: D col = lane&15 (pixel), row = lg*4+reg (o); nt out-store
#pragma unroll
    for (int m = 0; m < 2; ++m) {
#pragma unroll
        for (int r = 0; r < 4; ++r) {
            int o = (wid << 5) + (m << 4) + (lg << 2) + r;
            float bw = b_W[o];
            size_t rowbase = ((size_t)b * Cn + o) * HWn + p0;
#pragma unroll
            for (int n = 0; n < 2; ++n) {
                size_t idx = rowbase + (n << 4) + lr;
                __builtin_nontemporal_store(acc[m][n][r] + bw + x[idx], &out[idx]);
            }
        }
    }
}

extern "C" void kernel_launch(void* const* d_in, const int* in_sizes, int n_in,
                              void* d_out, int out_size, void* d_ws, size_t ws_size,
                              hipStream_t stream) {
    const float* x     = (const float*)d_in[0];
    const float* w_dw  = (const float*)d_in[1];
    const float* w_off = (const float*)d_in[2];
    const float* b_off = (const float*)d_in[3];
    const float* w_pc  = (const float*)d_in[4];
    const float* w_W   = (const float*)d_in[5];
    const float* b_W   = (const float*)d_in[6];
    float* out = (float*)d_out;

    char* ws = (char*)d_ws;
    unsigned short* x_t   = (unsigned short*)ws;                        // 67,108,864 B
    float2* coords        = (float2*)(ws + 67108864);                   //  1,048,576 B
    unsigned short* wcomb = (unsigned short*)(ws + 67108864 + 1048576); //    131,072 B

    build_wcomb<<<dim3(256), dim3(256), 0, stream>>>(w_dw, w_pc, w_W, wcomb);
    prep_kernel<<<dim3(2048), dim3(512), 0, stream>>>(x, w_off, b_off, x_t, coords);
    main_kernel<<<dim3(4096), dim3(512), 0, stream>>>(x, b_W, x_t, coords, wcomb, out);
}

// Round 18
// 114.026 us; speedup vs baseline: 1.0637x; 1.0188x over previous
//
#include <hip/hip_runtime.h>
#include <hip/hip_bf16.h>

#define Bn 8
#define Cn 256
#define Hn 128
#define Wn 128
#define HWn (Hn * Wn)

typedef __attribute__((ext_vector_type(8))) short bfrag8;       // MFMA A/B frag (8 bf16)
typedef __attribute__((ext_vector_type(8))) unsigned short u16x8;
typedef __attribute__((ext_vector_type(4))) unsigned short u16x4;
typedef __attribute__((ext_vector_type(4))) float f32x4;
typedef __attribute__((ext_vector_type(4))) unsigned int u32x4;

__device__ __forceinline__ float bf2f(unsigned short u) {
    unsigned int v = ((unsigned int)u) << 16;
    return __builtin_bit_cast(float, v);
}
__device__ __forceinline__ unsigned short f2bf(float f) {
    unsigned int u = __builtin_bit_cast(unsigned int, f);
    unsigned int lsb = (u >> 16) & 1u;
    u += 0x7fffu + lsb;   // round-to-nearest-even (finite inputs)
    return (unsigned short)(u >> 16);
}

// global->LDS DMA, 16 B per lane; dest = ldsbase + lane*16 (wave-uniform base)
__device__ __forceinline__ void load_lds16(const void* g, void* l) {
    __builtin_amdgcn_global_load_lds(
        (const __attribute__((address_space(1))) unsigned int*)g,
        (__attribute__((address_space(3))) unsigned int*)l,
        16, 0, 0);
}

// ---------------------------------------------------------------------------
// Kernel 0: w_comb2[o][c] = (sum_k w_W[o,k] * w_pc[k,c]) * w_dw[c], stored
// PRE-SWIZZLED in MFMA fragment order:
//   frag[ob][ks][lane][e] = w_comb2[ob*16 + (lane&15)][ks*32 + (lane>>4)*8 + e]
// ---------------------------------------------------------------------------
__global__ __launch_bounds__(256)
void build_wcomb(const float* __restrict__ w_dw,
                 const float* __restrict__ w_pc,
                 const float* __restrict__ w_W,
                 unsigned short* __restrict__ wfrag) {
    const int o = blockIdx.x;
    const int c = threadIdx.x;
    float acc = 0.f;
#pragma unroll 8
    for (int k = 0; k < Cn; ++k)
        acc = fmaf(w_W[o * Cn + k], w_pc[k * Cn + c], acc);
    const int ob = o >> 4, lr = o & 15;
    const int ks = c >> 5, lg = (c & 31) >> 3, e = c & 7;
    const int lane = (lg << 4) + lr;
    wfrag[((((ob << 3) + ks) << 6) + lane) * 8 + e] = f2bf(acc * w_dw[c]);
}

// ---------------------------------------------------------------------------
// Kernel 1: per 32-pixel tile, 256 threads, 18 KB LDS -> 8 blocks/CU
// (32 waves/CU, FULL occupancy). Channels in two 128-ch passes over one
// 16 KB buffer: dma(pass) -> sync -> conv(pass) -> sync. DMA: 8 rows/instr,
// 128 B contiguous per row, slot-swizzled (swz=(c^(c>>3))&7). Convert: wave
// owns 8 px as 4 pairs; lane (m=l>>5, octet=l&31) handles 4 ch of one px ->
// u16x4 store (wave store = 256 B/px, full lines). Offset dot accumulates
// in regs across passes; ONE shfl-reduce at the end -> tanh -> coords.
// ---------------------------------------------------------------------------
__global__ __launch_bounds__(256, 8)
void prep_kernel(const float* __restrict__ x,
                 const float* __restrict__ w_off,
                 const float* __restrict__ b_off,
                 unsigned short* __restrict__ x_t,    // [B*HW][C] bf16
                 float2* __restrict__ coords) {       // [B*HW] (ix, iy)
    __shared__ __align__(16) char tile[128 * 128];    // 128 ch x 32 px f32 (swizzled slots)
    __shared__ float woT[2][256];                     // [s][(pass<<7)+(j<<5)+octet]
    const int t = threadIdx.x;
    const int lane = t & 63;
    const int wv = t >> 6;                 // 0..3 (wave id)
    int blk = blockIdx.x;                  // 4096 blocks
    blk = ((blk & 7) << 9) | (blk >> 3);   // XCD swizzle: image b = XCD id
    const int b = blk >> 9;
    const int p0 = (blk & 511) << 5;       // 32-px tile
    const float* xp = x + ((size_t)b * Cn) * HWn + p0;

    // stage w_off transposed: woT[s][(pass<<7)+(j<<5)+octet] = w_off[s*256 + pass*128 + octet*4 + j]
    {
        const int pass = t >> 7, cl = t & 127;
        const int octet = cl >> 2, j = cl & 3;
#pragma unroll
        for (int s = 0; s < 2; ++s)
            woT[s][(pass << 7) + (j << 5) + octet] = w_off[(s << 8) + t];
    }

    const int m = lane >> 5;               // pair member
    const int octet = lane & 31;           // 4-channel group
    float s0[4] = {0.f, 0.f, 0.f, 0.f}, s1[4] = {0.f, 0.f, 0.f, 0.f};

#pragma unroll
    for (int pass = 0; pass < 2; ++pass) {
        // ---- DMA: 128 rows as 16 octo-row groups, 4 per wave ----
        {
            const int r = lane >> 3;       // row within group (0..7)
            const int q = lane & 7;        // slot (16B units)
#pragma unroll
            for (int i = 0; i < 4; ++i) {
                const int cbase = (wv << 5) + (i << 3);     // wave-uniform
                const int c = cbase + r;
                const int swz = (c ^ (c >> 3)) & 7;
                const float* src = xp + (size_t)((pass << 7) + c) * HWn + ((q ^ swz) << 2);
                load_lds16(src, tile + (cbase << 7));
            }
        }
        __syncthreads();   // DMA drained (+ woT on pass 0)

        // ---- convert: wave owns px [wv*8,+8) as 4 pairs ----
#pragma unroll
        for (int i = 0; i < 4; ++i) {
            const int px = (wv << 3) + (i << 1) + m;       // tile-local 0..31
            u16x4 res;
#pragma unroll
            for (int j = 0; j < 4; ++j) {
                const int c = (octet << 2) + j;            // 0..127
                const int swz = (c ^ (c >> 3)) & 7;
                const int byte = (c << 7) + ((((px >> 2) ^ swz)) << 4) + ((px & 3) << 2);
                float v = *reinterpret_cast<const float*>(tile + byte);
                s0[i] = fmaf(v, woT[0][(pass << 7) + (j << 5) + octet], s0[i]);
                s1[i] = fmaf(v, woT[1][(pass << 7) + (j << 5) + octet], s1[i]);
                res[j] = f2bf(v);
            }
            // wave store: 2 px x 32 octets x 8 B = 256 B contiguous per px
            *reinterpret_cast<u16x4*>(
                x_t + ((size_t)(b * HWn + p0 + px)) * Cn + (pass << 7) + (octet << 2)) = res;
        }
        __syncthreads();   // tile reuse safe (skip-able on last pass; harmless)
    }

    // ---- final offset reduce (once): per pair-half, per iteration slot ----
#pragma unroll
    for (int i = 0; i < 4; ++i) {
        float a = s0[i], c = s1[i];
        a += __shfl_xor(a, 1); a += __shfl_xor(a, 2); a += __shfl_xor(a, 4);
        a += __shfl_xor(a, 8); a += __shfl_xor(a, 16);
        c += __shfl_xor(c, 1); c += __shfl_xor(c, 2); c += __shfl_xor(c, 4);
        c += __shfl_xor(c, 8); c += __shfl_xor(c, 16);
        if (octet == 0) {
            const int px = (wv << 3) + (i << 1) + m;
            float o0 = tanhf(a + b_off[0]);
            float o1 = tanhf(c + b_off[1]);
            int p = p0 + px;
            int yy = p >> 7, xx = p & 127;
            float gx = fminf(fmaxf(-1.f + xx * (2.f / 127.f) + o0, -1.f), 1.f);
            float gy = fminf(fmaxf(-1.f + yy * (2.f / 127.f) + o1, -1.f), 1.f);
            // ix = ((gx+1)*W - 1)/2 = 64*gx + 63.5 ; same for iy (H=W=128)
            coords[(size_t)b * HWn + p] = make_float2(gx * 64.f + 63.5f, gy * 64.f + 63.5f);
        }
    }
}

// ---------------------------------------------------------------------------
// Kernel 2: per 32-pixel tile, 512 threads (8 waves). DMA-gather 4 corner LDS
// buffers (linear dest, source-swizzled chunks), sync, SINGLE blend pass
// (each (px,chunk) blended by exactly one thread, written in place into
// As[0] = samp), sync, MFMA (8 waves x 32-o slices) + fused epilogue.
//   out[o][p] = sum_c w_comb2[o][c]*samp[p][c] + b_W[o] + x[b][o][p]
// ---------------------------------------------------------------------------
__global__ __launch_bounds__(512, 2)
void main_kernel(const float* __restrict__ x,
                 const float* __restrict__ b_W,
                 const unsigned short* __restrict__ x_t,
                 const float2* __restrict__ coords,
                 const unsigned short* __restrict__ wfrag,
                 float* __restrict__ out) {
    __shared__ __align__(16) char As[4][32 * 512];   // 4 corners x 32px x 512B
    __shared__ __align__(16) float4 wts[32];         // per-pixel corner weights
    const int t = threadIdx.x;
    const int lane = t & 63;
    const int wid = t >> 6;          // 0..7
    int blk = blockIdx.x;            // 4096 blocks
    blk = ((blk & 7) << 9) | (blk >> 3);   // XCD swizzle: image b = XCD id
    const int b = blk >> 9;
    const int p0 = (blk & 511) << 5;       // 32-px tile
    const size_t pixbase = (size_t)b * HWn + p0;
    const unsigned short* xtb = x_t + (size_t)b * HWn * Cn;

    // ---- weights setup: one thread per pixel ----
    if (t < 32) {
        float2 co = coords[pixbase + t];
        float ix = co.x, iy = co.y;
        float fx = floorf(ix), fy = floorf(iy);
        int ix0 = (int)fx, iy0 = (int)fy;
        float wx1 = ix - fx, wy1 = iy - fy;
        float wx0 = 1.f - wx1, wy0 = 1.f - wy1;
        bool vx0 = (ix0 >= 0) && (ix0 < Wn);
        bool vx1 = (ix0 >= -1) && (ix0 < Wn - 1);
        bool vy0 = (iy0 >= 0) && (iy0 < Hn);
        bool vy1 = (iy0 >= -1) && (iy0 < Hn - 1);
        float4 w;
        w.x = (vy0 && vx0) ? wy0 * wx0 : 0.f;
        w.y = (vy0 && vx1) ? wy0 * wx1 : 0.f;
        w.z = (vy1 && vx0) ? wy1 * wx0 : 0.f;
        w.w = (vy1 && vx1) ? wy1 * wx1 : 0.f;
        wts[t] = w;
    }

    // ---- DMA gather: wave wid owns px [wid*4, wid*4+4) as 2 pixel-pairs ----
    {
        const int hp = lane >> 5;           // which pixel of the pair
        const int j = lane & 31;            // LDS chunk index (16B units)
        float2 co[2];
#pragma unroll
        for (int i = 0; i < 2; ++i)
            co[i] = coords[pixbase + (wid << 2) + (i << 1) + hp];

#pragma unroll
        for (int i = 0; i < 2; ++i) {
            const int p = (wid << 2) + (i << 1);   // pair base (wave-uniform)
            const int px = p + hp;                 // this lane's pixel
            float ix = co[i].x, iy = co[i].y;
            int ix0 = (int)floorf(ix), iy0 = (int)floorf(iy);
            int cx0 = min(max(ix0, 0), Wn - 1), cx1 = min(max(ix0 + 1, 0), Wn - 1);
            int cy0 = min(max(iy0, 0), Hn - 1), cy1 = min(max(iy0 + 1, 0), Hn - 1);
            const int gch = (j ^ (px & 15)) << 3;  // swizzled global channel base
            const unsigned short* s00 = xtb + (size_t)(cy0 * Wn + cx0) * Cn + gch;
            const unsigned short* s01 = xtb + (size_t)(cy0 * Wn + cx1) * Cn + gch;
            const unsigned short* s10 = xtb + (size_t)(cy1 * Wn + cx0) * Cn + gch;
            const unsigned short* s11 = xtb + (size_t)(cy1 * Wn + cx1) * Cn + gch;
            load_lds16(s00, &As[0][p << 9]);
            load_lds16(s01, &As[1][p << 9]);
            load_lds16(s10, &As[2][p << 9]);
            load_lds16(s11, &As[3][p << 9]);
        }
    }
    __syncthreads();   // drains DMA (vmcnt) + orders wts

    // ---- blend pass: each (px, chunk) by exactly one thread, in place ----
    {
        const int px = t >> 4;             // 0..31
        const float4 w = wts[px];
#pragma unroll
        for (int q = 0; q < 2; ++q) {
            const int kc = (t & 15) + (q << 4);          // 0..31
            const int off = (px << 9) + ((kc ^ (px & 15)) << 4);
            u16x8 c00 = *reinterpret_cast<const u16x8*>(&As[0][off]);
            u16x8 c01 = *reinterpret_cast<const u16x8*>(&As[1][off]);
            u16x8 c10 = *reinterpret_cast<const u16x8*>(&As[2][off]);
            u16x8 c11 = *reinterpret_cast<const u16x8*>(&As[3][off]);
            u16x8 res;
#pragma unroll
            for (int e = 0; e < 8; ++e) {
                float r = w.x * bf2f(c00[e]) + w.y * bf2f(c01[e])
                        + w.z * bf2f(c10[e]) + w.w * bf2f(c11[e]);
                res[e] = f2bf(r);
            }
            *reinterpret_cast<u16x8*>(&As[0][off]) = res;  // samp in place
        }
    }
    __syncthreads();

    // ---- MFMA phase: 8 waves; wave wid owns o-range [wid*32, +32), all 32 px
    const int lr = lane & 15;
    const int lg = lane >> 4;
    f32x4 acc[2][2];
#pragma unroll
    for (int m = 0; m < 2; ++m)
#pragma unroll
        for (int n = 0; n < 2; ++n)
            acc[m][n] = (f32x4){0.f, 0.f, 0.f, 0.f};

#pragma unroll
    for (int ks = 0; ks < 8; ++ks) {
        bfrag8 a[2], bb[2];
        const int kc = (ks << 2) + lg;           // 16B chunk index 0..31
#pragma unroll
        for (int n = 0; n < 2; ++n) {
            const int pr = (n << 4) + lr;
            const int off = (pr << 9) + ((kc ^ (pr & 15)) << 4);
            bb[n] = *reinterpret_cast<const bfrag8*>(&As[0][off]);
        }
#pragma unroll
        for (int m = 0; m < 2; ++m) {
            // coalesced fragment load: 64 lanes x 16 B contiguous (1 KB)
            const int ob = (wid << 1) + m;
            const unsigned short* src = wfrag + ((((ob << 3) + ks) << 6) + lane) * 8;
            a[m] = *reinterpret_cast<const bfrag8*>(src);
        }
#pragma unroll
        for (int m = 0; m < 2; ++m)
#pragma unroll
            for (int n = 0; n < 2; ++n)
                acc[m][n] = __builtin_amdgcn_mfma_f32_16x16x32_bf16(a[m], bb[n], acc[m][n], 0, 0, 0);
    }

    // ---- epilogue: D col = lane&15 (pixel), row = lg*4+reg (o); nt out-store
#pragma unroll
    for (int m = 0; m < 2; ++m) {
#pragma unroll
        for (int r = 0; r < 4; ++r) {
            int o = (wid << 5) + (m << 4) + (lg << 2) + r;
            float bw = b_W[o];
            size_t rowbase = ((size_t)b * Cn + o) * HWn + p0;
#pragma unroll
            for (int n = 0; n < 2; ++n) {
                size_t idx = rowbase + (n << 4) + lr;
                __builtin_nontemporal_store(acc[m][n][r] + bw + x[idx], &out[idx]);
            }
        }
    }
}

extern "C" void kernel_launch(void* const* d_in, const int* in_sizes, int n_in,
                              void* d_out, int out_size, void* d_ws, size_t ws_size,
                              hipStream_t stream) {
    const float* x     = (const float*)d_in[0];
    const float* w_dw  = (const float*)d_in[1];
    const float* w_off = (const float*)d_in[2];
    const float* b_off = (const float*)d_in[3];
    const float* w_pc  = (const float*)d_in[4];
    const float* w_W   = (const float*)d_in[5];
    const float* b_W   = (const float*)d_in[6];
    float* out = (float*)d_out;

    char* ws = (char*)d_ws;
    unsigned short* x_t   = (unsigned short*)ws;                        // 67,108,864 B
    float2* coords        = (float2*)(ws + 67108864);                   //  1,048,576 B
    unsigned short* wcomb = (unsigned short*)(ws + 67108864 + 1048576); //    131,072 B

    build_wcomb<<<dim3(256), dim3(256), 0, stream>>>(w_dw, w_pc, w_W, wcomb);
    prep_kernel<<<dim3(4096), dim3(256), 0, stream>>>(x, w_off, b_off, x_t, coords);
    main_kernel<<<dim3(4096), dim3(512), 0, stream>>>(x, b_W, x_t, coords, wcomb, out);
}

// Round 19
// 112.212 us; speedup vs baseline: 1.0809x; 1.0162x over previous
//
#include <hip/hip_runtime.h>
#include <hip/hip_bf16.h>

#define Bn 8
#define Cn 256
#define Hn 128
#define Wn 128
#define HWn (Hn * Wn)

typedef __attribute__((ext_vector_type(8))) short bfrag8;       // MFMA A/B frag (8 bf16)
typedef __attribute__((ext_vector_type(8))) unsigned short u16x8;
typedef __attribute__((ext_vector_type(4))) float f32x4;
typedef __attribute__((ext_vector_type(4))) unsigned int u32x4;

__device__ __forceinline__ float bf2f(unsigned short u) {
    unsigned int v = ((unsigned int)u) << 16;
    return __builtin_bit_cast(float, v);
}
__device__ __forceinline__ unsigned short f2bf(float f) {
    unsigned int u = __builtin_bit_cast(unsigned int, f);
    unsigned int lsb = (u >> 16) & 1u;
    u += 0x7fffu + lsb;   // round-to-nearest-even (finite inputs)
    return (unsigned short)(u >> 16);
}

// global->LDS DMA, 16 B per lane; dest = ldsbase + lane*16 (wave-uniform base)
__device__ __forceinline__ void load_lds16(const void* g, void* l) {
    __builtin_amdgcn_global_load_lds(
        (const __attribute__((address_space(1))) unsigned int*)g,
        (__attribute__((address_space(3))) unsigned int*)l,
        16, 0, 0);
}

// ---------------------------------------------------------------------------
// Kernel 0: w_comb2[o][c] = (sum_k w_W[o,k] * w_pc[k,c]) * w_dw[c], stored
// PRE-SWIZZLED in MFMA fragment order:
//   frag[ob][ks][lane][e] = w_comb2[ob*16 + (lane&15)][ks*32 + (lane>>4)*8 + e]
// ---------------------------------------------------------------------------
__global__ __launch_bounds__(256)
void build_wcomb(const float* __restrict__ w_dw,
                 const float* __restrict__ w_pc,
                 const float* __restrict__ w_W,
                 unsigned short* __restrict__ wfrag) {
    const int o = blockIdx.x;
    const int c = threadIdx.x;
    float acc = 0.f;
#pragma unroll 8
    for (int k = 0; k < Cn; ++k)
        acc = fmaf(w_W[o * Cn + k], w_pc[k * Cn + c], acc);
    const int ob = o >> 4, lr = o & 15;
    const int ks = c >> 5, lg = (c & 31) >> 3, e = c & 7;
    const int lane = (lg << 4) + lr;
    wfrag[((((ob << 3) + ks) << 6) + lane) * 8 + e] = f2bf(acc * w_dw[c]);
}

// ---------------------------------------------------------------------------
// Kernel 1: per 128-pixel tile, 256 threads, 4 blocks/CU (16 waves/CU).
// Channels in 8 passes of 32 ch over a DOUBLE-BUFFERED 16 KB LDS tile.
// DMA rows are 512 B CONTIGUOUS (1 instr = 2 rows x 512 B, 8 sequential
// lines per row visit). T3/T4 pipeline: dma(p+1) issued, then counted
// s_waitcnt vmcnt(4) (dma(p) done, dma(p+1) still flying) + raw s_barrier
// -> conv(p) overlaps dma(p+1) HBM latency. Linear LDS (reads are 2-way
// bank = free; no swizzle). Thread (px = t&127, h = t>>7) owns 16 ch:
// fused w_off dot accumulates in regs across all passes; tiny LDS reduce
// at the end -> tanh -> coords. x_t stores 32 B/thread (halves L2-merge).
// ---------------------------------------------------------------------------
__global__ __launch_bounds__(256, 4)
void prep_kernel(const float* __restrict__ x,
                 const float* __restrict__ w_off,
                 const float* __restrict__ b_off,
                 unsigned short* __restrict__ x_t,    // [B*HW][C] bf16
                 float2* __restrict__ coords) {       // [B*HW] (ix, iy)
    __shared__ __align__(16) float tile[2][32 * 128]; // 2 x 16 KB slice bufs
    __shared__ float wo[2][256];
    __shared__ float red[2][2][128];                  // [h][s][px]
    const int t = threadIdx.x;
    const int lane = t & 63;
    const int wv = t >> 6;                 // 0..3 (wave id)
    int blk = blockIdx.x;                  // 1024 blocks
    blk = ((blk & 7) << 7) | (blk >> 3);   // XCD swizzle: image b = XCD id
    const int b = blk >> 7;
    const int p0 = (blk & 127) << 7;       // 128-px tile
    const float* xp = x + ((size_t)b * Cn) * HWn + p0;

    // stage w_off (broadcast reads in convert)
    wo[0][t] = w_off[t];
    wo[1][t] = w_off[256 + t];

    const int px = t & 127;
    const int h = t >> 7;                  // channel half within pass
    float s0 = 0.f, s1 = 0.f;

    // DMA pass p: 32 rows as 16 two-row instrs (4/wave), rows 512 B contig
    auto dma = [&](int p) {
        float* buf = tile[p & 1];
        const int r = lane >> 5;           // row within pair
        const int q = lane & 31;           // 16 B slot within row
#pragma unroll
        for (int i = 0; i < 4; ++i) {
            const int cb = (wv << 3) + (i << 1);          // wave-uniform
            const float* src = xp + (size_t)((p << 5) + cb + r) * HWn + (q << 2);
            load_lds16(src, buf + (cb << 7));
        }
    };

    // convert pass p: 16 ch of pixel px; fused dot + bf16 pack + x_t store
    auto conv = [&](int p) {
        const float* buf = tile[p & 1];
        u16x8 r0, r1;
#pragma unroll
        for (int j = 0; j < 16; ++j) {
            const int cl = (h << 4) + j;
            float v = buf[(cl << 7) + px];
            s0 = fmaf(v, wo[0][(p << 5) + cl], s0);
            s1 = fmaf(v, wo[1][(p << 5) + cl], s1);
            if (j < 8) r0[j] = f2bf(v); else r1[j - 8] = f2bf(v);
        }
        unsigned short* dst = x_t + ((size_t)(b * HWn + p0 + px)) * Cn + (p << 5) + (h << 4);
        *reinterpret_cast<u16x8*>(dst) = r0;
        *reinterpret_cast<u16x8*>(dst + 8) = r1;
    };

    dma(0);
#pragma unroll
    for (int p = 0; p < 8; ++p) {
        if (p < 7) {
            dma(p + 1);                                        // next slice in flight
            asm volatile("s_waitcnt vmcnt(4) lgkmcnt(0)" ::: "memory"); // dma(p) done
        } else {
            asm volatile("s_waitcnt vmcnt(0) lgkmcnt(0)" ::: "memory");
        }
        __builtin_amdgcn_sched_barrier(0);
        __builtin_amdgcn_s_barrier();      // all waves: slice p landed
        __builtin_amdgcn_sched_barrier(0);
        conv(p);
        __builtin_amdgcn_s_barrier();      // all waves done reading buf p
        __builtin_amdgcn_sched_barrier(0);
    }

    // final offset reduce across the two channel-halves
    red[h][0][px] = s0;
    red[h][1][px] = s1;
    __syncthreads();
    if (t < 128) {
        float o0 = tanhf(red[0][0][t] + red[1][0][t] + b_off[0]);
        float o1 = tanhf(red[0][1][t] + red[1][1][t] + b_off[1]);
        int p = p0 + t;
        int yy = p >> 7, xx = p & 127;
        float gx = fminf(fmaxf(-1.f + xx * (2.f / 127.f) + o0, -1.f), 1.f);
        float gy = fminf(fmaxf(-1.f + yy * (2.f / 127.f) + o1, -1.f), 1.f);
        // ix = ((gx+1)*W - 1)/2 = 64*gx + 63.5 ; same for iy (H=W=128)
        coords[(size_t)b * HWn + p] = make_float2(gx * 64.f + 63.5f, gy * 64.f + 63.5f);
    }
}

// ---------------------------------------------------------------------------
// Kernel 2: per 32-pixel tile, 512 threads (8 waves). DMA-gather 4 corner LDS
// buffers (linear dest, source-swizzled chunks), sync, SINGLE blend pass
// (each (px,chunk) blended by exactly one thread, written in place into
// As[0] = samp), sync, MFMA (8 waves x 32-o slices) + fused epilogue.
//   out[o][p] = sum_c w_comb2[o][c]*samp[p][c] + b_W[o] + x[b][o][p]
// ---------------------------------------------------------------------------
__global__ __launch_bounds__(512, 2)
void main_kernel(const float* __restrict__ x,
                 const float* __restrict__ b_W,
                 const unsigned short* __restrict__ x_t,
                 const float2* __restrict__ coords,
                 const unsigned short* __restrict__ wfrag,
                 float* __restrict__ out) {
    __shared__ __align__(16) char As[4][32 * 512];   // 4 corners x 32px x 512B
    __shared__ __align__(16) float4 wts[32];         // per-pixel corner weights
    const int t = threadIdx.x;
    const int lane = t & 63;
    const int wid = t >> 6;          // 0..7
    int blk = blockIdx.x;            // 4096 blocks
    blk = ((blk & 7) << 9) | (blk >> 3);   // XCD swizzle: image b = XCD id
    const int b = blk >> 9;
    const int p0 = (blk & 511) << 5;       // 32-px tile
    const size_t pixbase = (size_t)b * HWn + p0;
    const unsigned short* xtb = x_t + (size_t)b * HWn * Cn;

    // ---- weights setup: one thread per pixel ----
    if (t < 32) {
        float2 co = coords[pixbase + t];
        float ix = co.x, iy = co.y;
        float fx = floorf(ix), fy = floorf(iy);
        int ix0 = (int)fx, iy0 = (int)fy;
        float wx1 = ix - fx, wy1 = iy - fy;
        float wx0 = 1.f - wx1, wy0 = 1.f - wy1;
        bool vx0 = (ix0 >= 0) && (ix0 < Wn);
        bool vx1 = (ix0 >= -1) && (ix0 < Wn - 1);
        bool vy0 = (iy0 >= 0) && (iy0 < Hn);
        bool vy1 = (iy0 >= -1) && (iy0 < Hn - 1);
        float4 w;
        w.x = (vy0 && vx0) ? wy0 * wx0 : 0.f;
        w.y = (vy0 && vx1) ? wy0 * wx1 : 0.f;
        w.z = (vy1 && vx0) ? wy1 * wx0 : 0.f;
        w.w = (vy1 && vx1) ? wy1 * wx1 : 0.f;
        wts[t] = w;
    }

    // ---- DMA gather: wave wid owns px [wid*4, wid*4+4) as 2 pixel-pairs ----
    {
        const int hp = lane >> 5;           // which pixel of the pair
        const int j = lane & 31;            // LDS chunk index (16B units)
        float2 co[2];
#pragma unroll
        for (int i = 0; i < 2; ++i)
            co[i] = coords[pixbase + (wid << 2) + (i << 1) + hp];

#pragma unroll
        for (int i = 0; i < 2; ++i) {
            const int p = (wid << 2) + (i << 1);   // pair base (wave-uniform)
            const int px = p + hp;                 // this lane's pixel
            float ix = co[i].x, iy = co[i].y;
            int ix0 = (int)floorf(ix), iy0 = (int)floorf(iy);
            int cx0 = min(max(ix0, 0), Wn - 1), cx1 = min(max(ix0 + 1, 0), Wn - 1);
            int cy0 = min(max(iy0, 0), Hn - 1), cy1 = min(max(iy0 + 1, 0), Hn - 1);
            const int gch = (j ^ (px & 15)) << 3;  // swizzled global channel base
            const unsigned short* s00 = xtb + (size_t)(cy0 * Wn + cx0) * Cn + gch;
            const unsigned short* s01 = xtb + (size_t)(cy0 * Wn + cx1) * Cn + gch;
            const unsigned short* s10 = xtb + (size_t)(cy1 * Wn + cx0) * Cn + gch;
            const unsigned short* s11 = xtb + (size_t)(cy1 * Wn + cx1) * Cn + gch;
            load_lds16(s00, &As[0][p << 9]);
            load_lds16(s01, &As[1][p << 9]);
            load_lds16(s10, &As[2][p << 9]);
            load_lds16(s11, &As[3][p << 9]);
        }
    }
    __syncthreads();   // drains DMA (vmcnt) + orders wts

    // ---- blend pass: each (px, chunk) by exactly one thread, in place ----
    {
        const int px = t >> 4;             // 0..31
        const float4 w = wts[px];
#pragma unroll
        for (int q = 0; q < 2; ++q) {
            const int kc = (t & 15) + (q << 4);          // 0..31
            const int off = (px << 9) + ((kc ^ (px & 15)) << 4);
            u16x8 c00 = *reinterpret_cast<const u16x8*>(&As[0][off]);
            u16x8 c01 = *reinterpret_cast<const u16x8*>(&As[1][off]);
            u16x8 c10 = *reinterpret_cast<const u16x8*>(&As[2][off]);
            u16x8 c11 = *reinterpret_cast<const u16x8*>(&As[3][off]);
            u16x8 res;
#pragma unroll
            for (int e = 0; e < 8; ++e) {
                float r = w.x * bf2f(c00[e]) + w.y * bf2f(c01[e])
                        + w.z * bf2f(c10[e]) + w.w * bf2f(c11[e]);
                res[e] = f2bf(r);
            }
            *reinterpret_cast<u16x8*>(&As[0][off]) = res;  // samp in place
        }
    }
    __syncthreads();

    // ---- MFMA phase: 8 waves; wave wid owns o-range [wid*32, +32), all 32 px
    const int lr = lane & 15;
    const int lg = lane >> 4;
    f32x4 acc[2][2];
#pragma unroll
    for (int m = 0; m < 2; ++m)
#pragma unroll
        for (int n = 0; n < 2; ++n)
            acc[m][n] = (f32x4){0.f, 0.f, 0.f, 0.f};

#pragma unroll
    for (int ks = 0; ks < 8; ++ks) {
        bfrag8 a[2], bb[2];
        const int kc = (ks << 2) + lg;           // 16B chunk index 0..31
#pragma unroll
        for (int n = 0; n < 2; ++n) {
            const int pr = (n << 4) + lr;
            const int off = (pr << 9) + ((kc ^ (pr & 15)) << 4);
            bb[n] = *reinterpret_cast<const bfrag8*>(&As[0][off]);
        }
#pragma unroll
        for (int m = 0; m < 2; ++m) {
            // coalesced fragment load: 64 lanes x 16 B contiguous (1 KB)
            const int ob = (wid << 1) + m;
            const unsigned short* src = wfrag + ((((ob << 3) + ks) << 6) + lane) * 8;
            a[m] = *reinterpret_cast<const bfrag8*>(src);
        }
#pragma unroll
        for (int m = 0; m < 2; ++m)
#pragma unroll
            for (int n = 0; n < 2; ++n)
                acc[m][n] = __builtin_amdgcn_mfma_f32_16x16x32_bf16(a[m], bb[n], acc[m][n], 0, 0, 0);
    }

    // ---- epilogue: D col = lane&15 (pixel), row = lg*4+reg (o); nt out-store
#pragma unroll
    for (int m = 0; m < 2; ++m) {
#pragma unroll
        for (int r = 0; r < 4; ++r) {
            int o = (wid << 5) + (m << 4) + (lg << 2) + r;
            float bw = b_W[o];
            size_t rowbase = ((size_t)b * Cn + o) * HWn + p0;
#pragma unroll
            for (int n = 0; n < 2; ++n) {
                size_t idx = rowbase + (n << 4) + lr;
                __builtin_nontemporal_store(acc[m][n][r] + bw + x[idx], &out[idx]);
            }
        }
    }
}

extern "C" void kernel_launch(void* const* d_in, const int* in_sizes, int n_in,
                              void* d_out, int out_size, void* d_ws, size_t ws_size,
                              hipStream_t stream) {
    const float* x     = (const float*)d_in[0];
    const float* w_dw  = (const float*)d_in[1];
    const float* w_off = (const float*)d_in[2];
    const float* b_off = (const float*)d_in[3];
    const float* w_pc  = (const float*)d_in[4];
    const float* w_W   = (const float*)d_in[5];
    const float* b_W   = (const float*)d_in[6];
    float* out = (float*)d_out;

    char* ws = (char*)d_ws;
    unsigned short* x_t   = (unsigned short*)ws;                        // 67,108,864 B
    float2* coords        = (float2*)(ws + 67108864);                   //  1,048,576 B
    unsigned short* wcomb = (unsigned short*)(ws + 67108864 + 1048576); //    131,072 B

    build_wcomb<<<dim3(256), dim3(256), 0, stream>>>(w_dw, w_pc, w_W, wcomb);
    prep_kernel<<<dim3(1024), dim3(256), 0, stream>>>(x, w_off, b_off, x_t, coords);
    main_kernel<<<dim3(4096), dim3(512), 0, stream>>>(x, b_W, x_t, coords, wcomb, out);
}